// Round 1
// baseline (107.155 us; speedup 1.0000x reference)
//
#include <hip/hip_runtime.h>
#include <math.h>

#define BB 256
#define DD 128
#define CC 8000
#define EPSF 1e-12f
#define SCALEF 64.0f
#define MARGINF 0.5f

// ---------------------------------------------------------------------------
// prep1: blocks 0..127 -> normalize embds rows (2 rows/block), store TRANSPOSED
//        neT[d*256 + r]. blocks 128..159 -> per-column rsqrt norms of w.
// ---------------------------------------------------------------------------
__global__ __launch_bounds__(256) void prep1_kernel(
    const float* __restrict__ embds, const float* __restrict__ w,
    float* __restrict__ neT, float* __restrict__ rcol) {
  __shared__ float part[4];
  int bid = blockIdx.x;
  int tid = threadIdx.x;
  if (bid < 128) {
    int half = tid >> 7;      // 0 or 1 (which row of the pair)
    int d = tid & 127;
    int r = 2 * bid + half;
    float v = embds[r * DD + d];
    float s = v * v;
    #pragma unroll
    for (int off = 32; off; off >>= 1) s += __shfl_down(s, off, 64);
    int wid = tid >> 6;
    if ((tid & 63) == 0) part[wid] = s;
    __syncthreads();
    float total = (half == 0) ? (part[0] + part[1]) : (part[2] + part[3]);
    float rn = rsqrtf(fmaxf(total, EPSF));
    neT[d * BB + r] = v * rn;   // transposed store [D][B]
  } else {
    int c = (bid - 128) * 256 + tid;
    if (c < CC) {
      float s = 0.f;
      #pragma unroll 4
      for (int d = 0; d < DD; ++d) {
        float v = w[d * CC + c];
        s = fmaf(v, v, s);
      }
      rcol[c] = rsqrtf(fmaxf(s, EPSF));
    }
  }
}

// ---------------------------------------------------------------------------
// prep2: per row b: gather g[b,d] = w[d,lab]*rcol[lab] (store transposed),
//        s1[b] = dot(ne[b], g[b]).  256 blocks x 128 threads.
// ---------------------------------------------------------------------------
__global__ __launch_bounds__(128) void prep2_kernel(
    const float* __restrict__ w, const int* __restrict__ labels,
    const float* __restrict__ rcol, const float* __restrict__ neT,
    float* __restrict__ gT, float* __restrict__ s1) {
  __shared__ float part[2];
  int b = blockIdx.x;
  int d = threadIdx.x;      // 128 threads
  int lab = labels[b];
  float gv = w[d * CC + lab] * rcol[lab];
  gT[d * BB + b] = gv;
  float p = gv * neT[d * BB + b];
  #pragma unroll
  for (int off = 32; off; off >>= 1) p += __shfl_down(p, off, 64);
  if ((d & 63) == 0) part[d >> 6] = p;
  __syncthreads();
  if (d == 0) s1[b] = part[0] + part[1];
}

// ---------------------------------------------------------------------------
// main: fused dual GEMM. Tile: 32 rows x 256 cols, 256 threads (4 waves).
// thread = 8 rows (by wave ty) x 4 cols (by lane tx). ne/g fragments broadcast
// from LDS (wave-uniform address), w streamed as float4 (L2-resident).
// Writes raw cos into logits region; penalties final.
// ---------------------------------------------------------------------------
__global__ __launch_bounds__(256) void main_kernel(
    const float* __restrict__ w, const float* __restrict__ rcol,
    const float* __restrict__ neT, const float* __restrict__ gT,
    const float* __restrict__ s1, const int* __restrict__ labels,
    float* __restrict__ out) {
  __shared__ float neS[DD * 32];
  __shared__ float gS[DD * 32];
  int tid = threadIdx.x;
  int c0 = blockIdx.x * 256;
  int r0 = blockIdx.y * 32;

  // Stage 32-row slices of neT/gT into LDS (straight float4 copy, conflict-free)
  {
    const float4* neT4 = (const float4*)neT;
    const float4* gT4 = (const float4*)gT;
    float4* neS4 = (float4*)neS;
    float4* gS4 = (float4*)gS;
    #pragma unroll
    for (int i4 = 0; i4 < 4; ++i4) {
      int idx = tid + i4 * 256;          // 0..1023
      int d = idx >> 3;                   // /8 float4s per 32-float row
      int r4 = idx & 7;
      int gsrc = d * (BB / 4) + (r0 >> 2) + r4;
      neS4[idx] = neT4[gsrc];
      gS4[idx] = gT4[gsrc];
    }
  }
  __syncthreads();

  int tx = tid & 63;
  int ty = tid >> 6;
  bool cok = (c0 + tx * 4) < CC;
  const float4* w4 = (const float4*)w;
  int wbase = (c0 >> 2) + tx;

  float accC[8][4];
  float accG[8][4];
  #pragma unroll
  for (int rr = 0; rr < 8; ++rr)
    #pragma unroll
    for (int j = 0; j < 4; ++j) { accC[rr][j] = 0.f; accG[rr][j] = 0.f; }

  #pragma unroll 4
  for (int d = 0; d < DD; ++d) {
    float4 wv = cok ? w4[d * (CC / 4) + wbase] : make_float4(0.f, 0.f, 0.f, 0.f);
    int base = d * 32 + ty * 8;
    float4 a0 = *(const float4*)&neS[base];
    float4 a1 = *(const float4*)&neS[base + 4];
    float4 g0 = *(const float4*)&gS[base];
    float4 g1 = *(const float4*)&gS[base + 4];
    float av[8] = {a0.x, a0.y, a0.z, a0.w, a1.x, a1.y, a1.z, a1.w};
    float gv[8] = {g0.x, g0.y, g0.z, g0.w, g1.x, g1.y, g1.z, g1.w};
    float wj[4] = {wv.x, wv.y, wv.z, wv.w};
    #pragma unroll
    for (int rr = 0; rr < 8; ++rr) {
      #pragma unroll
      for (int j = 0; j < 4; ++j) {
        accC[rr][j] = fmaf(av[rr], wj[j], accC[rr][j]);
        accG[rr][j] = fmaf(gv[rr], wj[j], accG[rr][j]);
      }
    }
  }

  if (!cok) return;
  float4 rc4 = ((const float4*)rcol)[wbase];
  float rcj[4] = {rc4.x, rc4.y, rc4.z, rc4.w};
  float* pen_base = out + (size_t)BB * CC;
  #pragma unroll
  for (int rr = 0; rr < 8; ++rr) {
    int r = r0 + ty * 8 + rr;
    float s1v = s1[r];
    int lab = labels[r];
    float cosv[4], penv[4];
    #pragma unroll
    for (int j = 0; j < 4; ++j) {
      float cs = accC[rr][j] * rcj[j];
      float gw = accG[rr][j] * rcj[j];
      float win = (s1v - cs) * rsqrtf(fmaxf(2.f - 2.f * gw, EPSF));
      int c = c0 + tx * 4 + j;
      if (c == lab) win = 0.f;
      cosv[j] = cs;
      penv[j] = MARGINF - fminf(MARGINF, win);
    }
    size_t o4 = (size_t)r * (CC / 4) + wbase;
    ((float4*)out)[o4] = make_float4(cosv[0], cosv[1], cosv[2], cosv[3]);
    ((float4*)pen_base)[o4] = make_float4(penv[0], penv[1], penv[2], penv[3]);
  }
}

// ---------------------------------------------------------------------------
// softmax: one block per row, in-place over the logits region (raw cos).
// logits = softmax(SCALE * cos) = exp(SCALE*(x-m)) / sum.
// ---------------------------------------------------------------------------
__global__ __launch_bounds__(256) void softmax_kernel(float* __restrict__ out) {
  __shared__ float red[4];
  int r = blockIdx.x;
  int tid = threadIdx.x;
  float4* row = (float4*)out + (size_t)r * (CC / 4);

  float4 vals[8];
  float m = -1e30f;
  #pragma unroll
  for (int k = 0; k < 8; ++k) {
    int i = tid + k * 256;
    if (i < CC / 4) {
      float4 v = row[i];
      vals[k] = v;
      m = fmaxf(m, fmaxf(fmaxf(v.x, v.y), fmaxf(v.z, v.w)));
    }
  }
  // block all-reduce max
  #pragma unroll
  for (int off = 1; off < 64; off <<= 1) m = fmaxf(m, __shfl_xor(m, off, 64));
  if ((tid & 63) == 0) red[tid >> 6] = m;
  __syncthreads();
  m = fmaxf(fmaxf(red[0], red[1]), fmaxf(red[2], red[3]));
  __syncthreads();

  float s = 0.f;
  #pragma unroll
  for (int k = 0; k < 8; ++k) {
    int i = tid + k * 256;
    if (i < CC / 4) {
      float4 v = vals[k];
      float4 e;
      e.x = __expf(SCALEF * (v.x - m));
      e.y = __expf(SCALEF * (v.y - m));
      e.z = __expf(SCALEF * (v.z - m));
      e.w = __expf(SCALEF * (v.w - m));
      vals[k] = e;
      s += e.x + e.y + e.z + e.w;
    }
  }
  #pragma unroll
  for (int off = 1; off < 64; off <<= 1) s += __shfl_xor(s, off, 64);
  if ((tid & 63) == 0) red[tid >> 6] = s;
  __syncthreads();
  s = red[0] + red[1] + red[2] + red[3];
  float inv = 1.f / s;

  #pragma unroll
  for (int k = 0; k < 8; ++k) {
    int i = tid + k * 256;
    if (i < CC / 4) {
      float4 e = vals[k];
      row[i] = make_float4(e.x * inv, e.y * inv, e.z * inv, e.w * inv);
    }
  }
}

extern "C" void kernel_launch(void* const* d_in, const int* in_sizes, int n_in,
                              void* d_out, int out_size, void* d_ws, size_t ws_size,
                              hipStream_t stream) {
  const float* embds = (const float*)d_in[0];
  const float* w = (const float*)d_in[1];
  const int* labels = (const int*)d_in[2];
  float* out = (float*)d_out;
  float* ws = (float*)d_ws;

  float* neT = ws;                 // [128][256] = 32768 floats
  float* gT = ws + 32768;          // [128][256] = 32768 floats
  float* rcol = ws + 65536;        // [8000]
  float* s1 = ws + 73536;          // [256]

  prep1_kernel<<<160, 256, 0, stream>>>(embds, w, neT, rcol);
  prep2_kernel<<<256, 128, 0, stream>>>(w, labels, rcol, neT, gT, s1);
  dim3 g3(32, 8);
  main_kernel<<<g3, 256, 0, stream>>>(w, rcol, neT, gT, s1, labels, out);
  softmax_kernel<<<256, 256, 0, stream>>>(out);
}

// Round 2
// 95.311 us; speedup vs baseline: 1.1243x; 1.1243x over previous
//
#include <hip/hip_runtime.h>
#include <math.h>

#define BB 256
#define DD 128
#define CC 8000
#define EPSF 1e-12f
#define SCALEF 64.0f
#define MARGINF 0.5f

// ---------------------------------------------------------------------------
// prep: one launch, no internal dependencies.
//   blocks 0..31   : rcol[c] = rsqrt(max(sum_d w[d,c]^2, eps))  (coalesced)
//   blocks 32..287 : per-row b: normalize embds row -> neT (transposed),
//                    gather w[:,lab], self-normalize -> gT, s1[b]=ne.g
// ---------------------------------------------------------------------------
__global__ __launch_bounds__(256) void prep_kernel(
    const float* __restrict__ embds, const float* __restrict__ w,
    const int* __restrict__ labels, float* __restrict__ neT,
    float* __restrict__ gT, float* __restrict__ rcol, float* __restrict__ s1) {
  int bid = blockIdx.x;
  int tid = threadIdx.x;
  if (bid < 32) {
    int c = bid * 256 + tid;
    if (c < CC) {
      float s = 0.f;
      #pragma unroll 8
      for (int d = 0; d < DD; ++d) {
        float v = w[d * CC + c];
        s = fmaf(v, v, s);
      }
      rcol[c] = rsqrtf(fmaxf(s, EPSF));
    }
  } else {
    __shared__ float red[3][2];
    int b = bid - 32;
    float e = 0.f, wl = 0.f;
    int d = tid;
    if (tid < 128) {
      int lab = labels[b];
      e = embds[b * DD + d];
      wl = w[d * CC + lab];
      float se = e * e, sw = wl * wl, sx = e * wl;
      #pragma unroll
      for (int off = 32; off; off >>= 1) {
        se += __shfl_down(se, off, 64);
        sw += __shfl_down(sw, off, 64);
        sx += __shfl_down(sx, off, 64);
      }
      if ((tid & 63) == 0) {
        int wid = tid >> 6;
        red[0][wid] = se; red[1][wid] = sw; red[2][wid] = sx;
      }
    }
    __syncthreads();
    if (tid < 128) {
      float Se = red[0][0] + red[0][1];
      float Sw = red[1][0] + red[1][1];
      float Sx = red[2][0] + red[2][1];
      float rn = rsqrtf(fmaxf(Se, EPSF));
      float rl = rsqrtf(fmaxf(Sw, EPSF));
      neT[d * BB + b] = e * rn;
      gT[d * BB + b] = wl * rl;
      if (tid == 0) s1[b] = Sx * rn * rl;
    }
  }
}

// ---------------------------------------------------------------------------
// main: fused dual GEMM. Tile 16 rows x 256 cols, 256 threads (4 waves).
// thread = 4 rows (ty=tid>>6) x 4 cols (tx=tid&63). Grid 32x16 = 512 blocks
// -> 2 blocks/CU, 8 waves/CU. LDS reads are wave-uniform (broadcast, free);
// w loads are 64 lanes x 16B = 1KB/instr, L2-resident after first row-block.
// Writes raw cos into logits region; penalties final.
// ---------------------------------------------------------------------------
__global__ __launch_bounds__(256) void main_kernel(
    const float* __restrict__ w, const float* __restrict__ rcol,
    const float* __restrict__ neT, const float* __restrict__ gT,
    const float* __restrict__ s1, const int* __restrict__ labels,
    float* __restrict__ out) {
  __shared__ float neS[DD * 16];
  __shared__ float gS[DD * 16];
  int tid = threadIdx.x;
  int c0 = blockIdx.x * 256;
  int r0 = blockIdx.y * 16;

  // Stage 16-row slices of neT/gT into LDS (float4 copy, conflict-free)
  {
    const float4* neT4 = (const float4*)neT;
    const float4* gT4 = (const float4*)gT;
    float4* neS4 = (float4*)neS;
    float4* gS4 = (float4*)gS;
    #pragma unroll
    for (int i4 = 0; i4 < 2; ++i4) {
      int idx = tid + i4 * 256;          // 0..511
      int d = idx >> 2;
      int r4 = idx & 3;
      int src = d * (BB / 4) + (r0 >> 2) + r4;
      neS4[idx] = neT4[src];
      gS4[idx] = gT4[src];
    }
  }
  __syncthreads();

  int tx = tid & 63;
  int ty = tid >> 6;
  int c = c0 + tx * 4;
  bool cok = c < CC;
  const float4* w4 = (const float4*)w;
  int wbase = (c0 >> 2) + tx;

  float accC[4][4];
  float accG[4][4];
  #pragma unroll
  for (int rr = 0; rr < 4; ++rr)
    #pragma unroll
    for (int j = 0; j < 4; ++j) { accC[rr][j] = 0.f; accG[rr][j] = 0.f; }

  #pragma unroll 8
  for (int d = 0; d < DD; ++d) {
    float4 wv = cok ? w4[d * (CC / 4) + wbase] : make_float4(0.f, 0.f, 0.f, 0.f);
    float4 a = *(const float4*)&neS[d * 16 + ty * 4];
    float4 g = *(const float4*)&gS[d * 16 + ty * 4];
    float av[4] = {a.x, a.y, a.z, a.w};
    float gv[4] = {g.x, g.y, g.z, g.w};
    float wj[4] = {wv.x, wv.y, wv.z, wv.w};
    #pragma unroll
    for (int rr = 0; rr < 4; ++rr) {
      #pragma unroll
      for (int j = 0; j < 4; ++j) {
        accC[rr][j] = fmaf(av[rr], wj[j], accC[rr][j]);
        accG[rr][j] = fmaf(gv[rr], wj[j], accG[rr][j]);
      }
    }
  }

  if (!cok) return;
  float4 rc4 = ((const float4*)rcol)[wbase];
  float rcj[4] = {rc4.x, rc4.y, rc4.z, rc4.w};
  float* pen_base = out + (size_t)BB * CC;
  #pragma unroll
  for (int rr = 0; rr < 4; ++rr) {
    int r = r0 + ty * 4 + rr;
    float s1v = s1[r];
    int lab = labels[r];
    float cosv[4], penv[4];
    #pragma unroll
    for (int j = 0; j < 4; ++j) {
      float cs = accC[rr][j] * rcj[j];
      float gw = accG[rr][j] * rcj[j];
      float win = (s1v - cs) * rsqrtf(fmaxf(2.f - 2.f * gw, EPSF));
      if (c + j == lab) win = 0.f;
      cosv[j] = cs;
      penv[j] = MARGINF - fminf(MARGINF, win);
    }
    size_t o4 = (size_t)r * (CC / 4) + wbase;
    ((float4*)out)[o4] = make_float4(cosv[0], cosv[1], cosv[2], cosv[3]);
    ((float4*)pen_base)[o4] = make_float4(penv[0], penv[1], penv[2], penv[3]);
  }
}

// ---------------------------------------------------------------------------
// softmax: one block per row (512 threads = 8 waves), in-place over logits
// region (raw cos, L2-warm). logits = exp(SCALE*(x-m)) / sum.
// ---------------------------------------------------------------------------
__global__ __launch_bounds__(512) void softmax_kernel(float* __restrict__ out) {
  __shared__ float red[8];
  int r = blockIdx.x;
  int tid = threadIdx.x;
  float4* row = (float4*)out + (size_t)r * (CC / 4);

  float4 vals[4];
  float m = -1e30f;
  #pragma unroll
  for (int k = 0; k < 4; ++k) {
    int i = tid + k * 512;
    if (i < CC / 4) {
      float4 v = row[i];
      vals[k] = v;
      m = fmaxf(m, fmaxf(fmaxf(v.x, v.y), fmaxf(v.z, v.w)));
    }
  }
  #pragma unroll
  for (int off = 1; off < 64; off <<= 1) m = fmaxf(m, __shfl_xor(m, off, 64));
  if ((tid & 63) == 0) red[tid >> 6] = m;
  __syncthreads();
  m = red[0];
  #pragma unroll
  for (int k = 1; k < 8; ++k) m = fmaxf(m, red[k]);
  __syncthreads();

  float s = 0.f;
  #pragma unroll
  for (int k = 0; k < 4; ++k) {
    int i = tid + k * 512;
    if (i < CC / 4) {
      float4 v = vals[k];
      float4 e;
      e.x = __expf(SCALEF * (v.x - m));
      e.y = __expf(SCALEF * (v.y - m));
      e.z = __expf(SCALEF * (v.z - m));
      e.w = __expf(SCALEF * (v.w - m));
      vals[k] = e;
      s += e.x + e.y + e.z + e.w;
    }
  }
  #pragma unroll
  for (int off = 1; off < 64; off <<= 1) s += __shfl_xor(s, off, 64);
  if ((tid & 63) == 0) red[tid >> 6] = s;
  __syncthreads();
  s = red[0];
  #pragma unroll
  for (int k = 1; k < 8; ++k) s += red[k];
  float inv = 1.f / s;

  #pragma unroll
  for (int k = 0; k < 4; ++k) {
    int i = tid + k * 512;
    if (i < CC / 4) {
      float4 e = vals[k];
      row[i] = make_float4(e.x * inv, e.y * inv, e.z * inv, e.w * inv);
    }
  }
}

extern "C" void kernel_launch(void* const* d_in, const int* in_sizes, int n_in,
                              void* d_out, int out_size, void* d_ws, size_t ws_size,
                              hipStream_t stream) {
  const float* embds = (const float*)d_in[0];
  const float* w = (const float*)d_in[1];
  const int* labels = (const int*)d_in[2];
  float* out = (float*)d_out;
  float* ws = (float*)d_ws;

  float* neT = ws;                 // [128][256] = 32768 floats
  float* gT = ws + 32768;          // [128][256] = 32768 floats
  float* rcol = ws + 65536;        // [8000]
  float* s1 = ws + 73536;          // [256]

  prep_kernel<<<288, 256, 0, stream>>>(embds, w, labels, neT, gT, rcol, s1);
  dim3 g3(32, 16);
  main_kernel<<<g3, 256, 0, stream>>>(w, rcol, neT, gT, s1, labels, out);
  softmax_kernel<<<256, 512, 0, stream>>>(out);
}

// Round 3
// 95.017 us; speedup vs baseline: 1.1277x; 1.0031x over previous
//
#include <hip/hip_runtime.h>
#include <math.h>

#define BB 256
#define DD 128
#define CC 8000
#define EPSF 1e-12f
#define SCALEF 64.0f
#define MARGINF 0.5f

// ---------------------------------------------------------------------------
// prep: one launch, no internal dependencies.
//   blocks 0..249   : rcol for 32 cols/block. threads = 32 cols x 8 d-groups,
//                     16 loads/thread (short dependency chains, high ILP).
//   blocks 250..505 : per-row b: normalize embds row -> neT (transposed),
//                     gather w[:,lab], self-normalize -> gT, s1[b]=ne.g
// ---------------------------------------------------------------------------
__global__ __launch_bounds__(256) void prep_kernel(
    const float* __restrict__ embds, const float* __restrict__ w,
    const int* __restrict__ labels, float* __restrict__ neT,
    float* __restrict__ gT, float* __restrict__ rcol, float* __restrict__ s1) {
  int bid = blockIdx.x;
  int tid = threadIdx.x;
  if (bid < 250) {
    __shared__ float partial[8][32];
    int col = tid & 31;
    int dg = tid >> 5;            // 0..7
    int c = bid * 32 + col;
    float s = 0.f;
    #pragma unroll
    for (int k = 0; k < 16; ++k) {
      float v = w[(dg * 16 + k) * CC + c];
      s = fmaf(v, v, s);
    }
    partial[dg][col] = s;
    __syncthreads();
    if (tid < 32) {
      float t = 0.f;
      #pragma unroll
      for (int k = 0; k < 8; ++k) t += partial[k][tid];
      rcol[bid * 32 + tid] = rsqrtf(fmaxf(t, EPSF));
    }
  } else {
    __shared__ float red[3][2];
    int b = bid - 250;
    float e = 0.f, wl = 0.f;
    int d = tid;
    if (tid < 128) {
      int lab = labels[b];
      e = embds[b * DD + d];
      wl = w[d * CC + lab];
      float se = e * e, sw = wl * wl, sx = e * wl;
      #pragma unroll
      for (int off = 32; off; off >>= 1) {
        se += __shfl_down(se, off, 64);
        sw += __shfl_down(sw, off, 64);
        sx += __shfl_down(sx, off, 64);
      }
      if ((tid & 63) == 0) {
        int wid = tid >> 6;
        red[0][wid] = se; red[1][wid] = sw; red[2][wid] = sx;
      }
    }
    __syncthreads();
    if (tid < 128) {
      float Se = red[0][0] + red[0][1];
      float Sw = red[1][0] + red[1][1];
      float Sx = red[2][0] + red[2][1];
      float rn = rsqrtf(fmaxf(Se, EPSF));
      float rl = rsqrtf(fmaxf(Sw, EPSF));
      neT[d * BB + b] = e * rn;
      gT[d * BB + b] = wl * rl;
      if (tid == 0) s1[b] = Sx * rn * rl;
    }
  }
}

// ---------------------------------------------------------------------------
// main: fused dual GEMM, NO LDS. Tile 16 rows x 256 cols, 256 threads.
// ne/g fragments are wave-uniform (depend only on d, ty) -> loaded via
// readfirstlane-forced uniform addresses so they compile to s_load_dwordx4
// (SMEM pipe, scalar-cache resident: 2KB/wave). Frees the LDS pipe entirely;
// kernel is VALU-bound. w streamed as float4 (64 lanes x 16B = 1KB/instr,
// L2-resident: each XCD sees c-tiles = id%8 -> 512KB of w).
// ---------------------------------------------------------------------------
__global__ __launch_bounds__(256) void main_kernel(
    const float* __restrict__ w, const float* __restrict__ rcol,
    const float* __restrict__ neT, const float* __restrict__ gT,
    const float* __restrict__ s1, const int* __restrict__ labels,
    float* __restrict__ out) {
  int tid = threadIdx.x;
  int c0 = blockIdx.x * 256;
  int r0 = blockIdx.y * 16;
  int tx = tid & 63;
  int tyu = __builtin_amdgcn_readfirstlane(tid >> 6);   // wave-uniform 0..3
  int rbase = r0 + tyu * 4;                              // uniform, mult of 4

  int c = c0 + tx * 4;
  bool cok = c < CC;
  const float4* w4 = (const float4*)w;
  const float4* neT4 = (const float4*)neT;
  const float4* gT4 = (const float4*)gT;
  int abase = rbase >> 2;                                // uniform float4 index

  float accC[4][4];
  float accG[4][4];
  #pragma unroll
  for (int rr = 0; rr < 4; ++rr)
    #pragma unroll
    for (int j = 0; j < 4; ++j) { accC[rr][j] = 0.f; accG[rr][j] = 0.f; }

  int wbase = (c0 >> 2) + tx;
  #pragma unroll 8
  for (int d = 0; d < DD; ++d) {
    float4 wv = cok ? w4[d * (CC / 4) + wbase] : make_float4(0.f, 0.f, 0.f, 0.f);
    float4 a = neT4[d * (BB / 4) + abase];   // uniform addr -> s_load_dwordx4
    float4 g = gT4[d * (BB / 4) + abase];    // uniform addr -> s_load_dwordx4
    float av[4] = {a.x, a.y, a.z, a.w};
    float gv[4] = {g.x, g.y, g.z, g.w};
    float wj[4] = {wv.x, wv.y, wv.z, wv.w};
    #pragma unroll
    for (int rr = 0; rr < 4; ++rr) {
      #pragma unroll
      for (int j = 0; j < 4; ++j) {
        accC[rr][j] = fmaf(av[rr], wj[j], accC[rr][j]);
        accG[rr][j] = fmaf(gv[rr], wj[j], accG[rr][j]);
      }
    }
  }

  if (!cok) return;
  float4 rc4 = ((const float4*)rcol)[wbase];
  float rcj[4] = {rc4.x, rc4.y, rc4.z, rc4.w};
  float* pen_base = out + (size_t)BB * CC;
  #pragma unroll
  for (int rr = 0; rr < 4; ++rr) {
    int r = rbase + rr;
    float s1v = s1[r];
    int lab = labels[r];
    float cosv[4], penv[4];
    #pragma unroll
    for (int j = 0; j < 4; ++j) {
      float cs = accC[rr][j] * rcj[j];
      float gw = accG[rr][j] * rcj[j];
      float win = (s1v - cs) * rsqrtf(fmaxf(2.f - 2.f * gw, EPSF));
      if (c + j == lab) win = 0.f;
      cosv[j] = cs;
      penv[j] = MARGINF - fminf(MARGINF, win);
    }
    size_t o4 = (size_t)r * (CC / 4) + wbase;
    ((float4*)out)[o4] = make_float4(cosv[0], cosv[1], cosv[2], cosv[3]);
    ((float4*)pen_base)[o4] = make_float4(penv[0], penv[1], penv[2], penv[3]);
  }
}

// ---------------------------------------------------------------------------
// softmax: one block per row (512 threads = 8 waves), in-place over logits
// region (raw cos, L2/L3-warm). logits = exp(SCALE*(x-m)) / sum.
// ---------------------------------------------------------------------------
__global__ __launch_bounds__(512) void softmax_kernel(float* __restrict__ out) {
  __shared__ float red[8];
  int r = blockIdx.x;
  int tid = threadIdx.x;
  float4* row = (float4*)out + (size_t)r * (CC / 4);

  float4 vals[4];
  float m = -1e30f;
  #pragma unroll
  for (int k = 0; k < 4; ++k) {
    int i = tid + k * 512;
    if (i < CC / 4) {
      float4 v = row[i];
      vals[k] = v;
      m = fmaxf(m, fmaxf(fmaxf(v.x, v.y), fmaxf(v.z, v.w)));
    }
  }
  #pragma unroll
  for (int off = 1; off < 64; off <<= 1) m = fmaxf(m, __shfl_xor(m, off, 64));
  if ((tid & 63) == 0) red[tid >> 6] = m;
  __syncthreads();
  m = red[0];
  #pragma unroll
  for (int k = 1; k < 8; ++k) m = fmaxf(m, red[k]);
  __syncthreads();

  float s = 0.f;
  #pragma unroll
  for (int k = 0; k < 4; ++k) {
    int i = tid + k * 512;
    if (i < CC / 4) {
      float4 v = vals[k];
      float4 e;
      e.x = __expf(SCALEF * (v.x - m));
      e.y = __expf(SCALEF * (v.y - m));
      e.z = __expf(SCALEF * (v.z - m));
      e.w = __expf(SCALEF * (v.w - m));
      vals[k] = e;
      s += e.x + e.y + e.z + e.w;
    }
  }
  #pragma unroll
  for (int off = 1; off < 64; off <<= 1) s += __shfl_xor(s, off, 64);
  if ((tid & 63) == 0) red[tid >> 6] = s;
  __syncthreads();
  s = red[0];
  #pragma unroll
  for (int k = 1; k < 8; ++k) s += red[k];
  float inv = 1.f / s;

  #pragma unroll
  for (int k = 0; k < 4; ++k) {
    int i = tid + k * 512;
    if (i < CC / 4) {
      float4 e = vals[k];
      row[i] = make_float4(e.x * inv, e.y * inv, e.z * inv, e.w * inv);
    }
  }
}

extern "C" void kernel_launch(void* const* d_in, const int* in_sizes, int n_in,
                              void* d_out, int out_size, void* d_ws, size_t ws_size,
                              hipStream_t stream) {
  const float* embds = (const float*)d_in[0];
  const float* w = (const float*)d_in[1];
  const int* labels = (const int*)d_in[2];
  float* out = (float*)d_out;
  float* ws = (float*)d_ws;

  float* neT = ws;                 // [128][256] = 32768 floats
  float* gT = ws + 32768;          // [128][256] = 32768 floats
  float* rcol = ws + 65536;        // [8000]
  float* s1 = ws + 73536;          // [256]

  prep_kernel<<<506, 256, 0, stream>>>(embds, w, labels, neT, gT, rcol, s1);
  dim3 g3(32, 16);
  main_kernel<<<g3, 256, 0, stream>>>(w, rcol, neT, gT, s1, labels, out);
  softmax_kernel<<<256, 512, 0, stream>>>(out);
}

// Round 5
// 94.606 us; speedup vs baseline: 1.1326x; 1.0043x over previous
//
#include <hip/hip_runtime.h>
#include <math.h>

#define BB 256
#define DD 128
#define CC 8000
#define EPSF 1e-12f
#define SCALEF 64.0f
#define MARGINF 0.5f

// ---------------------------------------------------------------------------
// Kernel A: fused prep + dual GEMM + epilogue. Grid 32(c) x 16(r) = 512
// blocks x 256 thr (2 blocks/CU, 8 waves/CU). Per block:
//   phase 1: local prep into LDS — normalize 16 embds rows (neS), gather+
//            normalize 16 label columns of w (gS), s1 per row.
//   phase 2: dual GEMM over d streaming w (float4, L2-resident). Column
//            norms accumulated FOR FREE from the same streamed w values.
//   phase 3: epilogue — penalties written final; e = exp(64*cos) written
//            UNNORMALIZED to the logits region (arg<=64 -> fits fp32, no
//            max-subtraction needed); per-(row,cblock) partial sums stored
//            to psums (no atomics).
// ---------------------------------------------------------------------------
__global__ __launch_bounds__(256, 2) void fused_kernel(
    const float* __restrict__ embds, const float* __restrict__ w,
    const int* __restrict__ labels, float* __restrict__ out,
    float* __restrict__ psums) {
  __shared__ float neS[DD * 16];
  __shared__ float gS[DD * 16];
  __shared__ float s1S[16];
  __shared__ int labS[16];

  int tid = threadIdx.x;
  int c0 = blockIdx.x * 256;
  int r0 = blockIdx.y * 16;

  // ---- phase 1: local prep (16 rows x 16 threads each) ----
  {
    int r = tid >> 4;           // 0..15 local row
    int k = tid & 15;           // 0..15, each handles 8 d's
    int row = r0 + r;
    int lab = labels[row];
    const float4* e4 = (const float4*)(embds + row * DD + k * 8);
    float4 ea = e4[0], eb = e4[1];
    float ev[8] = {ea.x, ea.y, ea.z, ea.w, eb.x, eb.y, eb.z, eb.w};
    float wl[8];
    float se = 0.f, sw = 0.f, sx = 0.f;
    #pragma unroll
    for (int i = 0; i < 8; ++i) {
      wl[i] = w[(k * 8 + i) * CC + lab];
      se = fmaf(ev[i], ev[i], se);
      sw = fmaf(wl[i], wl[i], sw);
      sx = fmaf(ev[i], wl[i], sx);
    }
    // reduce within the 16-lane k-group (xor masks 1,2,4,8 stay in-group)
    #pragma unroll
    for (int off = 1; off < 16; off <<= 1) {
      se += __shfl_xor(se, off, 64);
      sw += __shfl_xor(sw, off, 64);
      sx += __shfl_xor(sx, off, 64);
    }
    float rn = rsqrtf(fmaxf(se, EPSF));
    float rl = rsqrtf(fmaxf(sw, EPSF));
    #pragma unroll
    for (int i = 0; i < 8; ++i) {
      neS[(k * 8 + i) * 16 + r] = ev[i] * rn;
      gS[(k * 8 + i) * 16 + r] = wl[i] * rl;
    }
    if (k == 0) { s1S[r] = sx * rn * rl; labS[r] = lab; }
  }
  __syncthreads();

  // ---- phase 2: dual GEMM, w streamed once per block ----
  int tx = tid & 63;
  int ty = tid >> 6;            // wave id = row group (wave-uniform)
  int c = c0 + tx * 4;
  bool cok = c < CC;
  const float4* w4 = (const float4*)w;
  int wbase = (c0 >> 2) + tx;

  float accC[4][4], accG[4][4], colsum[4];
  #pragma unroll
  for (int rr = 0; rr < 4; ++rr)
    #pragma unroll
    for (int j = 0; j < 4; ++j) { accC[rr][j] = 0.f; accG[rr][j] = 0.f; }
  #pragma unroll
  for (int j = 0; j < 4; ++j) colsum[j] = 0.f;

  #pragma unroll 8
  for (int d = 0; d < DD; ++d) {
    float4 wv = cok ? w4[d * (CC / 4) + wbase] : make_float4(0.f, 0.f, 0.f, 0.f);
    float4 a = *(const float4*)&neS[d * 16 + ty * 4];  // wave-uniform: broadcast
    float4 g = *(const float4*)&gS[d * 16 + ty * 4];
    float av[4] = {a.x, a.y, a.z, a.w};
    float gv[4] = {g.x, g.y, g.z, g.w};
    float wj[4] = {wv.x, wv.y, wv.z, wv.w};
    #pragma unroll
    for (int j = 0; j < 4; ++j) colsum[j] = fmaf(wj[j], wj[j], colsum[j]);
    #pragma unroll
    for (int rr = 0; rr < 4; ++rr) {
      #pragma unroll
      for (int j = 0; j < 4; ++j) {
        accC[rr][j] = fmaf(av[rr], wj[j], accC[rr][j]);
        accG[rr][j] = fmaf(gv[rr], wj[j], accG[rr][j]);
      }
    }
  }

  // ---- phase 3: epilogue ----
  float rcj[4];
  #pragma unroll
  for (int j = 0; j < 4; ++j) rcj[j] = rsqrtf(fmaxf(colsum[j], EPSF));

  float* pen_base = out + (size_t)BB * CC;
  #pragma unroll
  for (int rr = 0; rr < 4; ++rr) {
    int lr = ty * 4 + rr;
    int row = r0 + lr;
    float s1v = s1S[lr];
    int lab = labS[lr];
    float penv[4], eo[4];
    float psum = 0.f;
    #pragma unroll
    for (int j = 0; j < 4; ++j) {
      float cs = accC[rr][j] * rcj[j];
      float gw = accG[rr][j] * rcj[j];
      float win = (s1v - cs) * rsqrtf(fmaxf(2.f - 2.f * gw, EPSF));
      if (c + j == lab) win = 0.f;
      penv[j] = MARGINF - fminf(MARGINF, win);
      float e = cok ? __expf(SCALEF * cs) : 0.f;
      eo[j] = e;
      psum += e;
    }
    if (cok) {
      size_t o4 = (size_t)row * (CC / 4) + wbase;
      ((float4*)pen_base)[o4] = make_float4(penv[0], penv[1], penv[2], penv[3]);
      ((float4*)out)[o4] = make_float4(eo[0], eo[1], eo[2], eo[3]);
    }
    // wave reduction of psum (all 64 lanes, this row)
    #pragma unroll
    for (int off = 1; off < 64; off <<= 1) psum += __shfl_xor(psum, off, 64);
    if (tx == 0) psums[row * 32 + blockIdx.x] = psum;
  }
}

// ---------------------------------------------------------------------------
// Kernel B: per-row normalize. 256 blocks x 512 thr. Sum the 32 partials,
// scale the row's 8000 unnormalized e-values in place.
// ---------------------------------------------------------------------------
__global__ __launch_bounds__(512) void scale_kernel(
    float* __restrict__ out, const float* __restrict__ psums) {
  __shared__ float invS;
  int r = blockIdx.x;
  int tid = threadIdx.x;
  if (tid < 64) {
    float p = (tid < 32) ? psums[r * 32 + tid] : 0.f;
    #pragma unroll
    for (int off = 1; off < 32; off <<= 1) p += __shfl_xor(p, off, 64);
    if (tid == 0) invS = 1.f / p;
  }
  __syncthreads();
  float inv = invS;
  float4* row = (float4*)out + (size_t)r * (CC / 4);
  #pragma unroll
  for (int k = 0; k < 4; ++k) {
    int i = tid + k * 512;
    if (i < CC / 4) {
      float4 v = row[i];
      row[i] = make_float4(v.x * inv, v.y * inv, v.z * inv, v.w * inv);
    }
  }
}

extern "C" void kernel_launch(void* const* d_in, const int* in_sizes, int n_in,
                              void* d_out, int out_size, void* d_ws, size_t ws_size,
                              hipStream_t stream) {
  const float* embds = (const float*)d_in[0];
  const float* w = (const float*)d_in[1];
  const int* labels = (const int*)d_in[2];
  float* out = (float*)d_out;
  float* psums = (float*)d_ws;    // [256][32]

  dim3 gA(32, 16);
  fused_kernel<<<gA, 256, 0, stream>>>(embds, w, labels, out, psums);
  scale_kernel<<<256, 512, 0, stream>>>(out, psums);
}